// Round 1
// baseline (377.048 us; speedup 1.0000x reference)
//
#include <hip/hip_runtime.h>
#include <math.h>

// Problem constants: B=16, Cin=32, Cout=32, H=W=256, m1=m2=16, modes kx in {0..15, 240..255}, ky in {0..15}
#define CIN   32
#define COUT  32
#define NKX   32   // 16 top + 16 bottom row-modes
#define M2    16

// ws layout (float2 units):
//   tab : float2[256]                      cos/sin(2*pi*k/256)
//   X   : float2[512 * 512]                [b*32+i][kxi][ky]  (B*Cin images x 32x16 modes)
//   Y   : float2[512 * 512]                [b*32+o][kxi][ky]

__global__ void init_tab(float2* __restrict__ tab) {
    int k = threadIdx.x;
    double a = (2.0 * M_PI / 256.0) * (double)k;
    tab[k] = make_float2((float)cos(a), (float)sin(a));
}

// ---------------- forward: per (b,i) image -> X[32 kx][16 ky] complex ----------------
__global__ __launch_bounds__(256) void fwd_dft(const float* __restrict__ x,
                                               const float2* __restrict__ tab,
                                               float2* __restrict__ X) {
    __shared__ float  xs[16][256];   // 16 rows of the image
    __shared__ float2 tabs[256];
    __shared__ float2 Tc[16][16];    // T[row][ky] for this chunk

    const int t = threadIdx.x;
    const int bi = blockIdx.x;                 // 0..511  (b*32+i)
    const float* xp = x + (size_t)bi * 65536;
    tabs[t] = tab[t];

    const int ky = t & 15;
    const int q  = t >> 4;                     // 0..15: role (a) row-in-chunk for T, (b) kx base for accum
    // outputs: (kxi=q, row r1=q) and (kxi=q+16, row r2=240+q)
    float x1r = 0.f, x1i = 0.f, x2r = 0.f, x2i = 0.f;

    for (int hc = 0; hc < 16; ++hc) {
        // stage 16 rows into LDS (coalesced float4)
        const float4* src = (const float4*)(xp + hc * 16 * 256);
        float4* dst = (float4*)(&xs[0][0]);
        #pragma unroll
        for (int p = 0; p < 4; ++p) dst[t + 256 * p] = src[t + 256 * p];
        __syncthreads();   // xs ready; also guarantees prior accumulate (Tc readers) finished

        // T[q][ky] = sum_w xs[q][w] * e^{-2pi i ky w/256}
        {
            float tr = 0.f, ti = 0.f;
            int idx = 0;
            const float* row = xs[q];
            #pragma unroll 8
            for (int w = 0; w < 256; ++w) {
                float  xv = row[w];
                float2 cs = tabs[idx];
                tr = fmaf(xv,  cs.x, tr);
                ti = fmaf(xv, -cs.y, ti);
                idx = (idx + ky) & 255;
            }
            Tc[q][ky] = make_float2(tr, ti);
        }
        __syncthreads();   // Tc ready

        // accumulate rows of this chunk into the two kx outputs
        #pragma unroll 4
        for (int hrel = 0; hrel < 16; ++hrel) {
            int h = hc * 16 + hrel;
            float2 tv = Tc[hrel][ky];
            float2 c1 = tabs[(q * h) & 255];
            float2 c2 = tabs[((q + 240) * h) & 255];
            // e^{-i th}: Xr += Tr*c + Ti*s ; Xi += Ti*c - Tr*s
            x1r = fmaf(tv.x, c1.x, fmaf( tv.y, c1.y, x1r));
            x1i = fmaf(tv.y, c1.x, fmaf(-tv.x, c1.y, x1i));
            x2r = fmaf(tv.x, c2.x, fmaf( tv.y, c2.y, x2r));
            x2i = fmaf(tv.y, c2.x, fmaf(-tv.x, c2.y, x2i));
        }
        __syncthreads();   // all Tc reads done before next chunk overwrites
    }

    float2* Xp = X + (size_t)bi * (NKX * M2);
    Xp[q * 16 + ky]        = make_float2(x1r, x1i);
    Xp[(q + 16) * 16 + ky] = make_float2(x2r, x2i);
}

// ---------------- mix: Y[b,o,kxi,ky] = sum_i X[b,i,kxi,ky] * W[i,o,kxi,ky] ----------------
__global__ __launch_bounds__(256) void mix(const float2* __restrict__ X,
                                           const float* __restrict__ w1r_, const float* __restrict__ w1i_,
                                           const float* __restrict__ w2r_, const float* __restrict__ w2i_,
                                           float2* __restrict__ Y) {
    int gid = blockIdx.x * 256 + threadIdx.x;  // (((b*32+o)*32+kxi)*16+ky)
    int ky  = gid & 15;
    int kxi = (gid >> 4) & 31;
    int o   = (gid >> 9) & 31;
    int b   = gid >> 14;
    const float* wr = (kxi < 16) ? w1r_ : w2r_;
    const float* wi = (kxi < 16) ? w1i_ : w2i_;
    int xx = kxi & 15;
    const float2* Xp  = X + (size_t)(b * CIN) * (NKX * M2) + kxi * M2 + ky;
    const float*  wrp = wr + ((size_t)o * 16 + xx) * 16 + ky;
    const float*  wip = wi + ((size_t)o * 16 + xx) * 16 + ky;
    float yr = 0.f, yi = 0.f;
    #pragma unroll 8
    for (int i = 0; i < CIN; ++i) {
        float2 xv  = Xp[i * (NKX * M2)];
        float  wre = wrp[i * (COUT * 16 * 16)];
        float  wim = wip[i * (COUT * 16 * 16)];
        yr = fmaf(xv.x, wre, fmaf(-xv.y, wim, yr));
        yi = fmaf(xv.x, wim, fmaf( xv.y, wre, yi));
    }
    Y[gid] = make_float2(yr, yi);
}

// ---------------- inverse: per (b,o, 16-row chunk) -> out rows ----------------
__global__ __launch_bounds__(256) void inv_dft(const float2* __restrict__ Y,
                                               const float2* __restrict__ tab,
                                               float* __restrict__ out) {
    __shared__ float2 Ys[NKX * M2];   // 512
    __shared__ float2 tabs[256];
    __shared__ float2 gs[16][16];

    const int t  = threadIdx.x;
    const int bo = blockIdx.x >> 4;   // 0..511 (b*32+o)
    const int hc = blockIdx.x & 15;
    tabs[t] = tab[t];
    Ys[t]       = Y[(size_t)bo * 512 + t];
    Ys[t + 256] = Y[(size_t)bo * 512 + t + 256];
    __syncthreads();

    // phase 1: g[hrel][ky] = (1/65536) * sum_kxi Y[kxi][ky] * e^{+2pi i r(kxi) h/256}
    {
        int hrel = t >> 4, ky = t & 15;
        int h = hc * 16 + hrel;
        float gr = 0.f, gi = 0.f;
        #pragma unroll
        for (int kxi = 0; kxi < 32; ++kxi) {
            int r = (kxi < 16) ? kxi : (kxi + 224);   // rows 0..15, 240..255
            float2 c  = tabs[(r * h) & 255];
            float2 yv = Ys[kxi * 16 + ky];
            // e^{+i th}: gr += Yr*c - Yi*s ; gi += Yr*s + Yi*c
            gr = fmaf(yv.x, c.x, fmaf(-yv.y, c.y, gr));
            gi = fmaf(yv.x, c.y, fmaf( yv.y, c.x, gi));
        }
        const float norm = 1.0f / 65536.0f;
        gs[hrel][ky] = make_float2(gr * norm, gi * norm);
    }
    __syncthreads();

    // phase 2: thread = w; out[h][w] = Re(g0) + 2*sum_{ky=1..15} (gr*cos - gi*sin)
    const int w = t;
    float* op = out + (size_t)bo * 65536 + (size_t)hc * 16 * 256 + w;
    #pragma unroll 2
    for (int hrel = 0; hrel < 16; ++hrel) {
        float acc = gs[hrel][0].x;
        float s2 = 0.f;
        int idx = w;                       // (1*w)&255
        #pragma unroll
        for (int ky = 1; ky < 16; ++ky) {
            float2 c = tabs[idx & 255];
            float2 g = gs[hrel][ky];
            s2 = fmaf(g.x, c.x, fmaf(-g.y, c.y, s2));
            idx += w;
        }
        op[hrel * 256] = fmaf(2.0f, s2, acc);
    }
}

extern "C" void kernel_launch(void* const* d_in, const int* in_sizes, int n_in,
                              void* d_out, int out_size, void* d_ws, size_t ws_size,
                              hipStream_t stream) {
    const float* x   = (const float*)d_in[0];
    const float* w1r = (const float*)d_in[1];
    const float* w1i = (const float*)d_in[2];
    const float* w2r = (const float*)d_in[3];
    const float* w2i = (const float*)d_in[4];
    float* out = (float*)d_out;

    float2* tab = (float2*)d_ws;
    float2* X   = tab + 256;
    float2* Yb  = X + 512 * 512;

    init_tab<<<1, 256, 0, stream>>>(tab);
    fwd_dft<<<512, 256, 0, stream>>>(x, tab, X);
    mix<<<1024, 256, 0, stream>>>(X, w1r, w1i, w2r, w2i, Yb);
    inv_dft<<<8192, 256, 0, stream>>>(Yb, tab, out);
}